// Round 17
// baseline (80.169 us; speedup 1.0000x reference)
//
#include <hip/hip_runtime.h>

// NearestNeighbor b=8, d=256, n=m=4096.
// Round 17: r16 + per-wave tile-order rotation (phase staggering) so the 2
// co-resident waves/SIMD overlap MFMA with fold instead of phase-locking.
// All math/layout byte-identical to verified r13/r16.

typedef unsigned int uint;
typedef unsigned char uchar;
typedef int i32x4 __attribute__((ext_vector_type(4)));
typedef int i32x8 __attribute__((ext_vector_type(8)));
typedef float f32x4 __attribute__((ext_vector_type(4)));

constexpr int B_ = 8, D_ = 256, N_ = 4096;
constexpr int CSPLIT = 4;
constexpr int MT_ITERS = (N_ / CSPLIT) / 128;   // 8 tiles of 128 cols

// Frag-tiled panel layout, contiguous 32B per lane (per batch, 1 MB):
// element (n,k): seg=n>>7, f=((n>>6)&1)*4+((n>>4)&3), i16=n&15;
//               ks=k>>7, g=(k>>5)&3, h=(k>>4)&1, kb=k&15, l=g*16+i16
// off = seg*32768 + ks*16384 + f*2048 + l*32 + h*16 + kb

// workspace layout (bytes)
constexpr size_t SZ_PANEL = (size_t)B_ * N_ * D_;        // 8.39 MB (fp8)
constexpr size_t OFF_AT = 0;
constexpr size_t OFF_BT = SZ_PANEL;
constexpr size_t OFF_PR = 2 * SZ_PANEL;                  // row partials: 8 slots
constexpr size_t SZ_PR  = (size_t)8 * B_ * N_ * 8;       // 2.1 MB
constexpr size_t OFF_PC = OFF_PR + SZ_PR;                // col partials: 64 slots

// f32 -> OCP e4m3fn (RNE, saturating).
__device__ __forceinline__ uchar f2e4m3(float f) {
  uint u = __float_as_uint(f);
  uint s = (u >> 24) & 0x80u;
  uint mag = u & 0x7FFFFFFFu;
  if (mag >= 0x43E00000u) return (uchar)(s | 0x7Eu);
  int e = (int)(mag >> 23) - 127;
  if (e >= -6) {
    uint m = (mag >> 20) & 7u;
    uint rem = mag & 0xFFFFFu;
    m += (rem > 0x80000u) || (rem == 0x80000u && (m & 1u));
    uint ef = (uint)(e + 7);
    if (m == 8u) { m = 0u; ef += 1u; }
    if (ef >= 16u) return (uchar)(s | 0x7Eu);
    return (uchar)(s | (ef << 3) | m);
  } else {
    int q = __float2int_rn(__uint_as_float(mag) * 512.0f);
    if (q >= 8) return (uchar)(s | 0x08u);
    return (uchar)(s | (uint)q);
  }
}

__device__ __forceinline__ float packkey(float v, uint mask, uint tag) {
  return __uint_as_float((__float_as_uint(v) & mask) | tag);
}

__device__ __forceinline__ float med3f(float a, float b, float c) {
#if __has_builtin(__builtin_amdgcn_fmed3f)
  return __builtin_amdgcn_fmed3f(a, b, c);
#else
  return fmaxf(fminf(a, b), fminf(fmaxf(a, b), c));
#endif
}

__device__ __forceinline__ void top2p(float& s1, float& s2, float k0, float k1) {
  const float mid = med3f(s1, k0, k1);
  s1 = fmaxf(fmaxf(s1, k0), k1);
  s2 = fmaxf(s2, mid);
}

__device__ __forceinline__ void top2merge(float& s1, float& s2, float o1, float o2) {
  const float lo = fminf(s1, o1);
  s1 = fmaxf(s1, o1);
  s2 = fmaxf(lo, fmaxf(s2, o2));
}

// ---- prep: [b][256][4096] f32 -> frag-tiled fp8 panel (verified r12-r16) ----
__global__ __launch_bounds__(256)
void prep_kernel(const float* __restrict__ in0, const float* __restrict__ in1,
                 uchar* __restrict__ At, uchar* __restrict__ Bt)
{
  __shared__ uchar tile[128][44];
  const int bz = blockIdx.z;
  const float* src = (bz < 8) ? in0 : in1;
  uchar* dst = (bz < 8) ? At : Bt;
  const int b = bz & 7;
  const int n0 = blockIdx.x * 128;
  const int k0b = blockIdx.y * 32;
  const int t = threadIdx.x;

  const int kq = t >> 5;
  const int n4 = (t & 31) * 4;
  const float* pin = src + ((size_t)b * D_ + k0b + kq * 4) * N_ + n0 + n4;
  float4 v[4];
  #pragma unroll
  for (int j = 0; j < 4; ++j) v[j] = *(const float4*)(pin + (size_t)j * N_);
  #pragma unroll
  for (int i = 0; i < 4; ++i) {
    uchar4 o = make_uchar4(f2e4m3(((const float*)&v[0])[i]),
                           f2e4m3(((const float*)&v[1])[i]),
                           f2e4m3(((const float*)&v[2])[i]),
                           f2e4m3(((const float*)&v[3])[i]));
    *(uchar4*)&tile[n4 + i][kq * 4] = o;
  }
  __syncthreads();

  const int nl = t & 127, h = t >> 7;
  const int kg = k0b + h * 16;
  const int ks = kg >> 7, g = (kg >> 5) & 3, hh = (kg >> 4) & 1;
  const int f = ((nl >> 6) & 1) * 4 + ((nl >> 4) & 3);
  const int l = g * 16 + (nl & 15);
  i32x4 val;
  #pragma unroll
  for (int j = 0; j < 4; ++j)
    val[j] = *(const int*)&tile[nl][h * 16 + j * 4];
  uchar* po = dst + (size_t)b * (N_ * D_) + (size_t)blockIdx.x * 32768 +
              ks * 16384 + f * 2048 + l * 32 + hh * 16;
  *(i32x4*)po = val;
}

// ---- fused GEMM (MX-fp8 K=128) + dual-direction top-2, NO LDS, NO barriers ----
// Block 256 thr = 4 waves (wm,wn), each 64x64 of a 128-row x 1024-col scan.
// Per-wave tile rotation staggers MFMA/fold phases across co-resident waves.
__global__ __launch_bounds__(256, 2)
void nn_pass(const uchar* __restrict__ A, const uchar* __restrict__ Bp,
             uint2* __restrict__ partR, uint2* __restrict__ partC)
{
  const int t = threadIdx.x;
  const int bid = blockIdx.x;
  const int b = bid & 7;                   // XCD-pinned batch (panels L2-resident)
  const int rb = (bid >> 3) & 31;
  const int cs = bid >> 8;                 // 0..3
  const size_t bOff = (size_t)b * (N_ * D_);
  const int r0 = rb * 128;

  const int l = t & 63, wid = t >> 6, wm = wid >> 1, wn = wid & 1;
  const int l15 = l & 15, g = l >> 4;
  const int rot = (((bid >> 3) * 3) + wid * 2) & 7;   // phase stagger

  const uchar* Aseg = A + bOff + (size_t)rb * 32768;
  const uchar* Bb = Bp + bOff + (size_t)cs * 262144;   // cs quarter: 8 tiles x 32KB

  // ---- A-frags resident in registers (64 VGPR) ----
  i32x8 af0[4], af1[4];
  #pragma unroll
  for (int mi = 0; mi < 4; ++mi) {
    af0[mi] = *(const i32x8*)(Aseg +         (wm * 4 + mi) * 2048 + l * 32);
    af1[mi] = *(const i32x8*)(Aseg + 16384 + (wm * 4 + mi) * 2048 + l * 32);
  }

  const float NEG = __uint_as_float(0xFF800000u);  // -inf
  float rs1[4][4], rs2[4][4];
  #pragma unroll
  for (int mi = 0; mi < 4; ++mi)
    #pragma unroll
    for (int rg = 0; rg < 4; ++rg) { rs1[mi][rg] = NEG; rs2[mi][rg] = NEG; }

  #pragma unroll 1
  for (int mt = 0; mt < MT_ITERS; ++mt) {
    const int mtw = (mt + rot) & 7;                  // this wave's tile
    const uchar* pB = Bb + (size_t)mtw * 32768 + wn * 8192 + l * 32;

    // 8 B-frags for this tile (both K-halves): 64 transient VGPR, L2-hot
    const i32x8 b00 = *(const i32x8*)(pB);
    const i32x8 b01 = *(const i32x8*)(pB + 2048);
    const i32x8 b02 = *(const i32x8*)(pB + 4096);
    const i32x8 b03 = *(const i32x8*)(pB + 6144);
    const i32x8 b10 = *(const i32x8*)(pB + 16384);
    const i32x8 b11 = *(const i32x8*)(pB + 16384 + 2048);
    const i32x8 b12 = *(const i32x8*)(pB + 16384 + 4096);
    const i32x8 b13 = *(const i32x8*)(pB + 16384 + 6144);

    f32x4 acc[4][4];
    #pragma unroll
    for (int mi = 0; mi < 4; ++mi)
      #pragma unroll
      for (int ni = 0; ni < 4; ++ni) acc[mi][ni] = (f32x4){0.f, 0.f, 0.f, 0.f};

    __builtin_amdgcn_s_setprio(1);
    #pragma unroll
    for (int mi = 0; mi < 4; ++mi) {
      acc[mi][0] = __builtin_amdgcn_mfma_scale_f32_16x16x128_f8f6f4(af0[mi], b00, acc[mi][0], 0, 0, 0, 127, 0, 127);
      acc[mi][1] = __builtin_amdgcn_mfma_scale_f32_16x16x128_f8f6f4(af0[mi], b01, acc[mi][1], 0, 0, 0, 127, 0, 127);
      acc[mi][2] = __builtin_amdgcn_mfma_scale_f32_16x16x128_f8f6f4(af0[mi], b02, acc[mi][2], 0, 0, 0, 127, 0, 127);
      acc[mi][3] = __builtin_amdgcn_mfma_scale_f32_16x16x128_f8f6f4(af0[mi], b03, acc[mi][3], 0, 0, 0, 127, 0, 127);
    }
    #pragma unroll
    for (int mi = 0; mi < 4; ++mi) {
      acc[mi][0] = __builtin_amdgcn_mfma_scale_f32_16x16x128_f8f6f4(af1[mi], b10, acc[mi][0], 0, 0, 0, 127, 0, 127);
      acc[mi][1] = __builtin_amdgcn_mfma_scale_f32_16x16x128_f8f6f4(af1[mi], b11, acc[mi][1], 0, 0, 0, 127, 0, 127);
      acc[mi][2] = __builtin_amdgcn_mfma_scale_f32_16x16x128_f8f6f4(af1[mi], b12, acc[mi][2], 0, 0, 0, 127, 0, 127);
      acc[mi][3] = __builtin_amdgcn_mfma_scale_f32_16x16x128_f8f6f4(af1[mi], b13, acc[mi][3], 0, 0, 0, 127, 0, 127);
    }
    __builtin_amdgcn_s_setprio(0);

    // ---- fold: row direction (persistent rs; 10-bit inv col tag) ----
    const int colb = mtw * 128 + wn * 64;
    const uint tg0 = (uint)(1023 - (colb + l15));
    #pragma unroll
    for (int mi = 0; mi < 4; ++mi)
      #pragma unroll
      for (int rg = 0; rg < 4; ++rg) {
        const float k0 = packkey(acc[mi][0][rg], 0xFFFFFC00u, tg0);
        const float k1 = packkey(acc[mi][1][rg], 0xFFFFFC00u, tg0 - 16);
        const float k2 = packkey(acc[mi][2][rg], 0xFFFFFC00u, tg0 - 32);
        const float k3 = packkey(acc[mi][3][rg], 0xFFFFFC00u, tg0 - 48);
        top2p(rs1[mi][rg], rs2[mi][rg], k0, k1);
        top2p(rs1[mi][rg], rs2[mi][rg], k2, k3);
      }

    // ---- fold: col direction (per tile; wave-private partC slot) ----
    const uint tgb = (uint)(63 - g * 4);
    #pragma unroll
    for (int ni = 0; ni < 4; ++ni) {
      float c1 = NEG, c2 = NEG;
      #pragma unroll
      for (int mi = 0; mi < 4; ++mi) {
        const float k0 = packkey(acc[mi][ni][0], 0xFFFFFFC0u, tgb - (uint)(mi * 16));
        const float k1 = packkey(acc[mi][ni][1], 0xFFFFFFC0u, tgb - (uint)(mi * 16 + 1));
        const float k2 = packkey(acc[mi][ni][2], 0xFFFFFFC0u, tgb - (uint)(mi * 16 + 2));
        const float k3 = packkey(acc[mi][ni][3], 0xFFFFFFC0u, tgb - (uint)(mi * 16 + 3));
        top2p(c1, c2, k0, k1);
        top2p(c1, c2, k2, k3);
      }
      #pragma unroll
      for (int off = 16; off <= 32; off <<= 1) {
        const float o1 = __shfl_xor(c1, off);
        const float o2 = __shfl_xor(c2, off);
        top2merge(c1, c2, o1, o2);
      }
      if (g == 0)
        partC[((size_t)(rb * 2 + wm) * B_ + b) * N_ + cs * 1024 + colb + ni * 16 + l15] =
            make_uint2(__float_as_uint(c1), __float_as_uint(c2));
    }
  }

  // epilogue: row merge across 16 column-lanes, write per-(cs,wn) partials
  #pragma unroll
  for (int off = 1; off < 16; off <<= 1) {
    #pragma unroll
    for (int mi = 0; mi < 4; ++mi)
      #pragma unroll
      for (int rg = 0; rg < 4; ++rg) {
        const float o1 = __shfl_xor(rs1[mi][rg], off);
        const float o2 = __shfl_xor(rs2[mi][rg], off);
        top2merge(rs1[mi][rg], rs2[mi][rg], o1, o2);
      }
  }
  if (l15 == 0) {
    #pragma unroll
    for (int mi = 0; mi < 4; ++mi)
      #pragma unroll
      for (int rg = 0; rg < 4; ++rg)
        partR[((size_t)(cs * 2 + wn) * B_ + b) * N_ + r0 + wm * 64 + mi * 16 + g * 4 + rg] =
            make_uint2(__float_as_uint(rs1[mi][rg]), __float_as_uint(rs2[mi][rg]));
  }
}

// ---- fused: fold partials, ratio test, mutual check, output (verified r14-r16) ----
__global__ __launch_bounds__(256)
void finalize_kernel(const uint2* __restrict__ pR, const uint2* __restrict__ pC,
                     float* __restrict__ out)
{
  const int i = blockIdx.x * 256 + threadIdx.x;
  if (i >= B_ * N_) return;
  const int b = i >> 12;
  const int n = i & (N_ - 1);
  const float NEG = __uint_as_float(0xFF800000u);

  float s1 = NEG, s2 = NEG; int bs = 0;
  #pragma unroll
  for (int sl = 0; sl < 8; ++sl) {
    const uint2 v = pR[(size_t)sl * B_ * N_ + i];
    const float o1 = __uint_as_float(v.x), o2 = __uint_as_float(v.y);
    bs = (o1 > s1) ? sl : bs;
    top2merge(s1, s2, o1, o2);
  }
  const uint k1 = __float_as_uint(s1);
  const int col = (bs >> 1) * 1024 + 1023 - (int)(k1 & 0x3FFu);
  const float v1 = __uint_as_float(k1 & 0xFFFFFC00u);
  const float v2 = __uint_as_float(__float_as_uint(s2) & 0xFFFFFC00u);
  const bool ok = (1.0f - v1) <= 0.64f * (1.0f - v2);   // Lowe 0.8^2

  out[B_ * N_ + i] = ok ? (v1 + 1.0f) * 0.5f : 0.0f;    // scores0 (no mutual mask)

  int res = -1;
  if (ok) {
    float c1 = NEG, c2 = NEG; int cbs = 0;
    const uint2* pcb = pC + (size_t)b * N_ + col;
    #pragma unroll 8
    for (int sl = 0; sl < 64; ++sl) {
      const uint2 v = pcb[(size_t)sl * B_ * N_];
      const float o1 = __uint_as_float(v.x), o2 = __uint_as_float(v.y);
      cbs = (o1 > c1) ? sl : cbs;
      top2merge(c1, c2, o1, o2);
    }
    const uint ck1 = __float_as_uint(c1);
    const int row = cbs * 64 + 63 - (int)(ck1 & 0x3Fu);
    const float cv1 = __uint_as_float(ck1 & 0xFFFFFFC0u);
    const float cv2 = __uint_as_float(__float_as_uint(c2) & 0xFFFFFFC0u);
    const bool cok = (1.0f - cv1) <= 0.64f * (1.0f - cv2);
    if (cok && row == n) res = col;
  }
  out[i] = (float)res;
}

extern "C" void kernel_launch(void* const* d_in, const int* in_sizes, int n_in,
                              void* d_out, int out_size, void* d_ws, size_t ws_size,
                              hipStream_t stream)
{
  const float* d0 = (const float*)d_in[0];
  const float* d1 = (const float*)d_in[1];
  float* out = (float*)d_out;

  uchar* At = (uchar*)((char*)d_ws + OFF_AT);
  uchar* Bt = (uchar*)((char*)d_ws + OFF_BT);
  uint2* PR = (uint2*)((char*)d_ws + OFF_PR);
  uint2* PC = (uint2*)((char*)d_ws + OFF_PC);

  prep_kernel<<<dim3(N_ / 128, D_ / 32, 16), 256, 0, stream>>>(d0, d1, At, Bt);
  nn_pass<<<dim3(B_ * 32 * CSPLIT), 256, 0, stream>>>(At, Bt, PR, PC);
  finalize_kernel<<<dim3(B_ * N_ / 256), 256, 0, stream>>>(PR, PC, out);
}

// Round 18
// 75.757 us; speedup vs baseline: 1.0582x; 1.0582x over previous
//
#include <hip/hip_runtime.h>

// NearestNeighbor b=8, d=256, n=m=4096.
// Round 18: r16 + loop-carried ks0 prefetch (pf0..pf3, static names) issued
// after MFMA-half1 so the fold covers next tile's L2 latency. No LDS, no
// barriers. All math/layout byte-identical to verified r13/r16.

typedef unsigned int uint;
typedef unsigned char uchar;
typedef int i32x4 __attribute__((ext_vector_type(4)));
typedef int i32x8 __attribute__((ext_vector_type(8)));
typedef float f32x4 __attribute__((ext_vector_type(4)));

constexpr int B_ = 8, D_ = 256, N_ = 4096;
constexpr int CSPLIT = 4;
constexpr int MT_ITERS = (N_ / CSPLIT) / 128;   // 8 tiles of 128 cols

// Frag-tiled panel layout, contiguous 32B per lane (per batch, 1 MB):
// element (n,k): seg=n>>7, f=((n>>6)&1)*4+((n>>4)&3), i16=n&15;
//               ks=k>>7, g=(k>>5)&3, h=(k>>4)&1, kb=k&15, l=g*16+i16
// off = seg*32768 + ks*16384 + f*2048 + l*32 + h*16 + kb

// workspace layout (bytes)
constexpr size_t SZ_PANEL = (size_t)B_ * N_ * D_;        // 8.39 MB (fp8)
constexpr size_t OFF_AT = 0;
constexpr size_t OFF_BT = SZ_PANEL;
constexpr size_t OFF_PR = 2 * SZ_PANEL;                  // row partials: 8 slots
constexpr size_t SZ_PR  = (size_t)8 * B_ * N_ * 8;       // 2.1 MB
constexpr size_t OFF_PC = OFF_PR + SZ_PR;                // col partials: 64 slots

// f32 -> OCP e4m3fn (RNE, saturating).
__device__ __forceinline__ uchar f2e4m3(float f) {
  uint u = __float_as_uint(f);
  uint s = (u >> 24) & 0x80u;
  uint mag = u & 0x7FFFFFFFu;
  if (mag >= 0x43E00000u) return (uchar)(s | 0x7Eu);
  int e = (int)(mag >> 23) - 127;
  if (e >= -6) {
    uint m = (mag >> 20) & 7u;
    uint rem = mag & 0xFFFFFu;
    m += (rem > 0x80000u) || (rem == 0x80000u && (m & 1u));
    uint ef = (uint)(e + 7);
    if (m == 8u) { m = 0u; ef += 1u; }
    if (ef >= 16u) return (uchar)(s | 0x7Eu);
    return (uchar)(s | (ef << 3) | m);
  } else {
    int q = __float2int_rn(__uint_as_float(mag) * 512.0f);
    if (q >= 8) return (uchar)(s | 0x08u);
    return (uchar)(s | (uint)q);
  }
}

__device__ __forceinline__ float packkey(float v, uint mask, uint tag) {
  return __uint_as_float((__float_as_uint(v) & mask) | tag);
}

__device__ __forceinline__ float med3f(float a, float b, float c) {
#if __has_builtin(__builtin_amdgcn_fmed3f)
  return __builtin_amdgcn_fmed3f(a, b, c);
#else
  return fmaxf(fminf(a, b), fminf(fmaxf(a, b), c));
#endif
}

__device__ __forceinline__ void top2p(float& s1, float& s2, float k0, float k1) {
  const float mid = med3f(s1, k0, k1);
  s1 = fmaxf(fmaxf(s1, k0), k1);
  s2 = fmaxf(s2, mid);
}

__device__ __forceinline__ void top2merge(float& s1, float& s2, float o1, float o2) {
  const float lo = fminf(s1, o1);
  s1 = fmaxf(s1, o1);
  s2 = fmaxf(lo, fmaxf(s2, o2));
}

// ---- prep: [b][256][4096] f32 -> frag-tiled fp8 panel (verified r12-r17) ----
__global__ __launch_bounds__(256)
void prep_kernel(const float* __restrict__ in0, const float* __restrict__ in1,
                 uchar* __restrict__ At, uchar* __restrict__ Bt)
{
  __shared__ uchar tile[128][44];
  const int bz = blockIdx.z;
  const float* src = (bz < 8) ? in0 : in1;
  uchar* dst = (bz < 8) ? At : Bt;
  const int b = bz & 7;
  const int n0 = blockIdx.x * 128;
  const int k0b = blockIdx.y * 32;
  const int t = threadIdx.x;

  const int kq = t >> 5;
  const int n4 = (t & 31) * 4;
  const float* pin = src + ((size_t)b * D_ + k0b + kq * 4) * N_ + n0 + n4;
  float4 v[4];
  #pragma unroll
  for (int j = 0; j < 4; ++j) v[j] = *(const float4*)(pin + (size_t)j * N_);
  #pragma unroll
  for (int i = 0; i < 4; ++i) {
    uchar4 o = make_uchar4(f2e4m3(((const float*)&v[0])[i]),
                           f2e4m3(((const float*)&v[1])[i]),
                           f2e4m3(((const float*)&v[2])[i]),
                           f2e4m3(((const float*)&v[3])[i]));
    *(uchar4*)&tile[n4 + i][kq * 4] = o;
  }
  __syncthreads();

  const int nl = t & 127, h = t >> 7;
  const int kg = k0b + h * 16;
  const int ks = kg >> 7, g = (kg >> 5) & 3, hh = (kg >> 4) & 1;
  const int f = ((nl >> 6) & 1) * 4 + ((nl >> 4) & 3);
  const int l = g * 16 + (nl & 15);
  i32x4 val;
  #pragma unroll
  for (int j = 0; j < 4; ++j)
    val[j] = *(const int*)&tile[nl][h * 16 + j * 4];
  uchar* po = dst + (size_t)b * (N_ * D_) + (size_t)blockIdx.x * 32768 +
              ks * 16384 + f * 2048 + l * 32 + hh * 16;
  *(i32x4*)po = val;
}

// ---- fused GEMM (MX-fp8 K=128) + dual-direction top-2, NO LDS, NO barriers ----
// Block 256 thr = 4 waves (wm,wn), each 64x64 of a 128-row x 1024-col scan.
// Loop-carried ks0 prefetch: next tile's b0x loads hide under this tile's fold.
__global__ __launch_bounds__(256, 2)
void nn_pass(const uchar* __restrict__ A, const uchar* __restrict__ Bp,
             uint2* __restrict__ partR, uint2* __restrict__ partC)
{
  const int t = threadIdx.x;
  const int bid = blockIdx.x;
  const int b = bid & 7;                   // XCD-pinned batch (panels L2-resident)
  const int rb = (bid >> 3) & 31;
  const int cs = bid >> 8;                 // 0..3
  const size_t bOff = (size_t)b * (N_ * D_);
  const int r0 = rb * 128;

  const int l = t & 63, wid = t >> 6, wm = wid >> 1, wn = wid & 1;
  const int l15 = l & 15, g = l >> 4;

  const uchar* Aseg = A + bOff + (size_t)rb * 32768;
  const uchar* Bb = Bp + bOff + (size_t)cs * 262144;   // cs quarter: 8 tiles x 32KB

  // ---- A-frags resident in registers (64 VGPR) ----
  i32x8 af0[4], af1[4];
  #pragma unroll
  for (int mi = 0; mi < 4; ++mi) {
    af0[mi] = *(const i32x8*)(Aseg +         (wm * 4 + mi) * 2048 + l * 32);
    af1[mi] = *(const i32x8*)(Aseg + 16384 + (wm * 4 + mi) * 2048 + l * 32);
  }

  const float NEG = __uint_as_float(0xFF800000u);  // -inf
  float rs1[4][4], rs2[4][4];
  #pragma unroll
  for (int mi = 0; mi < 4; ++mi)
    #pragma unroll
    for (int rg = 0; rg < 4; ++rg) { rs1[mi][rg] = NEG; rs2[mi][rg] = NEG; }

  // ---- prologue: prefetch tile 0's ks0 frags (loop-carried, static names) ----
  const uchar* pB0 = Bb + wn * 8192 + l * 32;
  i32x8 pf0 = *(const i32x8*)(pB0);
  i32x8 pf1 = *(const i32x8*)(pB0 + 2048);
  i32x8 pf2 = *(const i32x8*)(pB0 + 4096);
  i32x8 pf3 = *(const i32x8*)(pB0 + 6144);

  #pragma unroll 1
  for (int mt = 0; mt < MT_ITERS; ++mt) {
    const uchar* pB = Bb + (size_t)mt * 32768 + wn * 8192 + l * 32;

    // ks1 frags for this tile (covered by half-0 MFMAs below)
    const i32x8 b10 = *(const i32x8*)(pB + 16384);
    const i32x8 b11 = *(const i32x8*)(pB + 16384 + 2048);
    const i32x8 b12 = *(const i32x8*)(pB + 16384 + 4096);
    const i32x8 b13 = *(const i32x8*)(pB + 16384 + 6144);

    f32x4 acc[4][4];
    #pragma unroll
    for (int mi = 0; mi < 4; ++mi)
      #pragma unroll
      for (int ni = 0; ni < 4; ++ni) acc[mi][ni] = (f32x4){0.f, 0.f, 0.f, 0.f};

    // ---- MFMA half ks=0 (uses prefetched pf*) ----
    __builtin_amdgcn_s_setprio(1);
    #pragma unroll
    for (int mi = 0; mi < 4; ++mi) {
      acc[mi][0] = __builtin_amdgcn_mfma_scale_f32_16x16x128_f8f6f4(af0[mi], pf0, acc[mi][0], 0, 0, 0, 127, 0, 127);
      acc[mi][1] = __builtin_amdgcn_mfma_scale_f32_16x16x128_f8f6f4(af0[mi], pf1, acc[mi][1], 0, 0, 0, 127, 0, 127);
      acc[mi][2] = __builtin_amdgcn_mfma_scale_f32_16x16x128_f8f6f4(af0[mi], pf2, acc[mi][2], 0, 0, 0, 127, 0, 127);
      acc[mi][3] = __builtin_amdgcn_mfma_scale_f32_16x16x128_f8f6f4(af0[mi], pf3, acc[mi][3], 0, 0, 0, 127, 0, 127);
    }
    // ---- MFMA half ks=1 ----
    #pragma unroll
    for (int mi = 0; mi < 4; ++mi) {
      acc[mi][0] = __builtin_amdgcn_mfma_scale_f32_16x16x128_f8f6f4(af1[mi], b10, acc[mi][0], 0, 0, 0, 127, 0, 127);
      acc[mi][1] = __builtin_amdgcn_mfma_scale_f32_16x16x128_f8f6f4(af1[mi], b11, acc[mi][1], 0, 0, 0, 127, 0, 127);
      acc[mi][2] = __builtin_amdgcn_mfma_scale_f32_16x16x128_f8f6f4(af1[mi], b12, acc[mi][2], 0, 0, 0, 127, 0, 127);
      acc[mi][3] = __builtin_amdgcn_mfma_scale_f32_16x16x128_f8f6f4(af1[mi], b13, acc[mi][3], 0, 0, 0, 127, 0, 127);
    }
    __builtin_amdgcn_s_setprio(0);

    // ---- prefetch NEXT tile's ks0 (L2 latency hides under the fold below) ----
    {
      const uchar* pN = Bb + (size_t)((mt + 1) & 7) * 32768 + wn * 8192 + l * 32;
      pf0 = *(const i32x8*)(pN);
      pf1 = *(const i32x8*)(pN + 2048);
      pf2 = *(const i32x8*)(pN + 4096);
      pf3 = *(const i32x8*)(pN + 6144);
    }

    // ---- fold: row direction (persistent rs; 10-bit inv col tag) ----
    const int colb = mt * 128 + wn * 64;
    const uint tg0 = (uint)(1023 - (colb + l15));
    #pragma unroll
    for (int mi = 0; mi < 4; ++mi)
      #pragma unroll
      for (int rg = 0; rg < 4; ++rg) {
        const float k0 = packkey(acc[mi][0][rg], 0xFFFFFC00u, tg0);
        const float k1 = packkey(acc[mi][1][rg], 0xFFFFFC00u, tg0 - 16);
        const float k2 = packkey(acc[mi][2][rg], 0xFFFFFC00u, tg0 - 32);
        const float k3 = packkey(acc[mi][3][rg], 0xFFFFFC00u, tg0 - 48);
        top2p(rs1[mi][rg], rs2[mi][rg], k0, k1);
        top2p(rs1[mi][rg], rs2[mi][rg], k2, k3);
      }

    // ---- fold: col direction (per tile; wave-private partC slot) ----
    const uint tgb = (uint)(63 - g * 4);
    #pragma unroll
    for (int ni = 0; ni < 4; ++ni) {
      float c1 = NEG, c2 = NEG;
      #pragma unroll
      for (int mi = 0; mi < 4; ++mi) {
        const float k0 = packkey(acc[mi][ni][0], 0xFFFFFFC0u, tgb - (uint)(mi * 16));
        const float k1 = packkey(acc[mi][ni][1], 0xFFFFFFC0u, tgb - (uint)(mi * 16 + 1));
        const float k2 = packkey(acc[mi][ni][2], 0xFFFFFFC0u, tgb - (uint)(mi * 16 + 2));
        const float k3 = packkey(acc[mi][ni][3], 0xFFFFFFC0u, tgb - (uint)(mi * 16 + 3));
        top2p(c1, c2, k0, k1);
        top2p(c1, c2, k2, k3);
      }
      #pragma unroll
      for (int off = 16; off <= 32; off <<= 1) {
        const float o1 = __shfl_xor(c1, off);
        const float o2 = __shfl_xor(c2, off);
        top2merge(c1, c2, o1, o2);
      }
      if (g == 0)
        partC[((size_t)(rb * 2 + wm) * B_ + b) * N_ + cs * 1024 + colb + ni * 16 + l15] =
            make_uint2(__float_as_uint(c1), __float_as_uint(c2));
    }
  }

  // epilogue: row merge across 16 column-lanes, write per-(cs,wn) partials
  #pragma unroll
  for (int off = 1; off < 16; off <<= 1) {
    #pragma unroll
    for (int mi = 0; mi < 4; ++mi)
      #pragma unroll
      for (int rg = 0; rg < 4; ++rg) {
        const float o1 = __shfl_xor(rs1[mi][rg], off);
        const float o2 = __shfl_xor(rs2[mi][rg], off);
        top2merge(rs1[mi][rg], rs2[mi][rg], o1, o2);
      }
  }
  if (l15 == 0) {
    #pragma unroll
    for (int mi = 0; mi < 4; ++mi)
      #pragma unroll
      for (int rg = 0; rg < 4; ++rg)
        partR[((size_t)(cs * 2 + wn) * B_ + b) * N_ + r0 + wm * 64 + mi * 16 + g * 4 + rg] =
            make_uint2(__float_as_uint(rs1[mi][rg]), __float_as_uint(rs2[mi][rg]));
  }
}

// ---- fused: fold partials, ratio test, mutual check, output (verified r14-r17) ----
__global__ __launch_bounds__(256)
void finalize_kernel(const uint2* __restrict__ pR, const uint2* __restrict__ pC,
                     float* __restrict__ out)
{
  const int i = blockIdx.x * 256 + threadIdx.x;
  if (i >= B_ * N_) return;
  const int b = i >> 12;
  const int n = i & (N_ - 1);
  const float NEG = __uint_as_float(0xFF800000u);

  float s1 = NEG, s2 = NEG; int bs = 0;
  #pragma unroll
  for (int sl = 0; sl < 8; ++sl) {
    const uint2 v = pR[(size_t)sl * B_ * N_ + i];
    const float o1 = __uint_as_float(v.x), o2 = __uint_as_float(v.y);
    bs = (o1 > s1) ? sl : bs;
    top2merge(s1, s2, o1, o2);
  }
  const uint k1 = __float_as_uint(s1);
  const int col = (bs >> 1) * 1024 + 1023 - (int)(k1 & 0x3FFu);
  const float v1 = __uint_as_float(k1 & 0xFFFFFC00u);
  const float v2 = __uint_as_float(__float_as_uint(s2) & 0xFFFFFC00u);
  const bool ok = (1.0f - v1) <= 0.64f * (1.0f - v2);   // Lowe 0.8^2

  out[B_ * N_ + i] = ok ? (v1 + 1.0f) * 0.5f : 0.0f;    // scores0 (no mutual mask)

  int res = -1;
  if (ok) {
    float c1 = NEG, c2 = NEG; int cbs = 0;
    const uint2* pcb = pC + (size_t)b * N_ + col;
    #pragma unroll 8
    for (int sl = 0; sl < 64; ++sl) {
      const uint2 v = pcb[(size_t)sl * B_ * N_];
      const float o1 = __uint_as_float(v.x), o2 = __uint_as_float(v.y);
      cbs = (o1 > c1) ? sl : cbs;
      top2merge(c1, c2, o1, o2);
    }
    const uint ck1 = __float_as_uint(c1);
    const int row = cbs * 64 + 63 - (int)(ck1 & 0x3Fu);
    const float cv1 = __uint_as_float(ck1 & 0xFFFFFFC0u);
    const float cv2 = __uint_as_float(__float_as_uint(c2) & 0xFFFFFFC0u);
    const bool cok = (1.0f - cv1) <= 0.64f * (1.0f - cv2);
    if (cok && row == n) res = col;
  }
  out[i] = (float)res;
}

extern "C" void kernel_launch(void* const* d_in, const int* in_sizes, int n_in,
                              void* d_out, int out_size, void* d_ws, size_t ws_size,
                              hipStream_t stream)
{
  const float* d0 = (const float*)d_in[0];
  const float* d1 = (const float*)d_in[1];
  float* out = (float*)d_out;

  uchar* At = (uchar*)((char*)d_ws + OFF_AT);
  uchar* Bt = (uchar*)((char*)d_ws + OFF_BT);
  uint2* PR = (uint2*)((char*)d_ws + OFF_PR);
  uint2* PC = (uint2*)((char*)d_ws + OFF_PC);

  prep_kernel<<<dim3(N_ / 128, D_ / 32, 16), 256, 0, stream>>>(d0, d1, At, Bt);
  nn_pass<<<dim3(B_ * 32 * CSPLIT), 256, 0, stream>>>(At, Bt, PR, PC);
  finalize_kernel<<<dim3(B_ * N_ / 256), 256, 0, stream>>>(PR, PC, out);
}